// Round 4
// baseline (1478.798 us; speedup 1.0000x reference)
//
#include <hip/hip_runtime.h>
#include <float.h>
#include <math.h>

#define HIDDEN 2048
#define ROUTE_H 256
#define NEXP 64
#define BATCH 32
#define SEQ 4096
#define TOPK 8
#define LN_EPS 1e-5f

// ---------------------------------------------------------------------------
// Kernel 1: partial mean-pool. grid = BATCH*nchunks, block = 256.
// Each block sums `rows` consecutive seq rows of one batch into partial[blk][0:2048].
// Thread t owns float4 lanes t and t+256 (H=2048 floats = 512 float4).
__global__ __launch_bounds__(256) void pool_partial_k(
    const float* __restrict__ x, float* __restrict__ partial,
    int nchunks, int rows) {
  int blk = blockIdx.x;
  int b = blk / nchunks;
  int c = blk - b * nchunks;
  int t = threadIdx.x;
  const float4* xb = (const float4*)x + (size_t)(b * SEQ + c * rows) * (HIDDEN / 4);
  float4 a0 = make_float4(0.f, 0.f, 0.f, 0.f);
  float4 a1 = make_float4(0.f, 0.f, 0.f, 0.f);
  #pragma unroll 4
  for (int s = 0; s < rows; ++s) {
    const float4* row = xb + (size_t)s * (HIDDEN / 4);
    float4 v0 = row[t];
    float4 v1 = row[t + 256];
    a0.x += v0.x; a0.y += v0.y; a0.z += v0.z; a0.w += v0.w;
    a1.x += v1.x; a1.y += v1.y; a1.z += v1.z; a1.w += v1.w;
  }
  float4* p = (float4*)partial + (size_t)blk * (HIDDEN / 4);
  p[t] = a0;
  p[t + 256] = a1;
}

// ---------------------------------------------------------------------------
// Kernel 2: reduce partials -> pooled[b][h] (mean). grid = BATCH*HIDDEN/256.
__global__ __launch_bounds__(256) void pool_reduce_k(
    const float* __restrict__ partial, float* __restrict__ pooled, int nchunks) {
  int g = blockIdx.x * 256 + threadIdx.x;  // [0, BATCH*HIDDEN)
  int b = g / HIDDEN;
  int h = g - b * HIDDEN;
  float s = 0.f;
  #pragma unroll 8
  for (int c = 0; c < nchunks; ++c)
    s += partial[(size_t)(b * nchunks + c) * HIDDEN + h];
  pooled[g] = s * (1.0f / SEQ);
}

// ---------------------------------------------------------------------------
// Block-wide (256-thread) sum: wave64 shuffle reduce + LDS across 4 waves.
__device__ inline float blk_sum256(float v, float* red) {
  #pragma unroll
  for (int off = 32; off > 0; off >>= 1) v += __shfl_xor(v, off, 64);
  int wave = threadIdx.x >> 6;
  if ((threadIdx.x & 63) == 0) red[wave] = v;
  __syncthreads();
  float r = red[0] + red[1] + red[2] + red[3];
  __syncthreads();
  return r;
}

// Kernel 3: per-batch router MLP + LN + GELU + top-k softmax scatter.
// grid = BATCH, block = 256 (= ROUTE_H).
__global__ __launch_bounds__(256) void router_k(
    const float* __restrict__ pooled,
    const float* __restrict__ W1, const float* __restrict__ b1,
    const float* __restrict__ lng, const float* __restrict__ lnb,
    const float* __restrict__ W2, const float* __restrict__ b2,
    float* __restrict__ out) {
  __shared__ float pooled_s[HIDDEN];
  __shared__ float act_s[ROUTE_H];
  __shared__ float red_s[4];
  int b = blockIdx.x;
  int t = threadIdx.x;

  // stage pooled row into LDS
  #pragma unroll
  for (int i = 0; i < HIDDEN / ROUTE_H; ++i)
    pooled_s[t + i * ROUTE_H] = pooled[(size_t)b * HIDDEN + t + i * ROUTE_H];
  __syncthreads();

  // h = pooled @ W1 + b1 : thread t computes column t (coalesced W1 reads)
  float hr = b1[t];
  #pragma unroll 8
  for (int h = 0; h < HIDDEN; ++h)
    hr += pooled_s[h] * W1[(size_t)h * ROUTE_H + t];

  // LayerNorm over ROUTE_H (two-pass: mean, then variance)
  float mu = blk_sum256(hr, red_s) * (1.0f / ROUTE_H);
  float d = hr - mu;
  float var = blk_sum256(d * d, red_s) * (1.0f / ROUTE_H);
  float xn = d * rsqrtf(var + LN_EPS) * lng[t] + lnb[t];

  // exact GELU: x * 0.5 * (1 + erf(x / sqrt(2)))
  float g = 0.5f * xn * (1.0f + erff(xn * 0.70710678118654752f));
  act_s[t] = g;
  __syncthreads();

  // logits + top-k + softmax + scatter, all within the first wave
  if (t < NEXP) {
    float le = b2[t];
    #pragma unroll 8
    for (int j = 0; j < ROUTE_H; ++j)
      le += act_s[j] * W2[(size_t)j * NEXP + t];

    // iterative top-8 via wave arg-max (tie-break: lower index, as lax.top_k)
    float cur = le;
    float topv[TOPK];
    int topi[TOPK];
    #pragma unroll
    for (int k = 0; k < TOPK; ++k) {
      float v = cur;
      int idx = t;
      #pragma unroll
      for (int off = 32; off > 0; off >>= 1) {
        float ov = __shfl_xor(v, off, 64);
        int oi = __shfl_xor(idx, off, 64);
        if (ov > v || (ov == v && oi < idx)) { v = ov; idx = oi; }
      }
      topv[k] = v;  // uniform across lanes
      topi[k] = idx;
      if (t == idx) cur = -FLT_MAX;
    }

    // softmax over the 8 selected (temperature = 1.0)
    float m = topv[0];
    float w[TOPK];
    float sum = 0.f;
    #pragma unroll
    for (int k = 0; k < TOPK; ++k) { w[k] = expf(topv[k] - m); sum += w[k]; }
    float inv = 1.0f / sum;

    // each lane writes exactly one output element: 0 or its selected weight
    float o = 0.f;
    #pragma unroll
    for (int k = 0; k < TOPK; ++k)
      if (topi[k] == t) o = w[k] * inv;
    out[b * NEXP + t] = o;
  }
}

// ---------------------------------------------------------------------------
extern "C" void kernel_launch(void* const* d_in, const int* in_sizes, int n_in,
                              void* d_out, int out_size, void* d_ws, size_t ws_size,
                              hipStream_t stream) {
  const float* x   = (const float*)d_in[0];  // [B, S, H]
  const float* W1  = (const float*)d_in[1];  // [H, ROUTE_H]
  const float* b1  = (const float*)d_in[2];  // [ROUTE_H]
  const float* lng = (const float*)d_in[3];  // [ROUTE_H]
  const float* lnb = (const float*)d_in[4];  // [ROUTE_H]
  const float* W2  = (const float*)d_in[5];  // [ROUTE_H, NEXP]
  const float* b2  = (const float*)d_in[6];  // [NEXP]
  // d_in[7] = top_k scalar (= 8), compile-time fixed
  float* out = (float*)d_out;

  // workspace layout: [partial: B*nchunks*H floats][pooled: B*H floats]
  size_t pooled_bytes = (size_t)BATCH * HIDDEN * sizeof(float);
  int nchunks = 64;
  while (nchunks > 1 &&
         (size_t)BATCH * nchunks * HIDDEN * sizeof(float) + pooled_bytes > ws_size)
    nchunks >>= 1;
  int rows = SEQ / nchunks;
  float* partial = (float*)d_ws;
  float* pooled = partial + (size_t)BATCH * nchunks * HIDDEN;

  pool_partial_k<<<BATCH * nchunks, 256, 0, stream>>>(x, partial, nchunks, rows);
  pool_reduce_k<<<(BATCH * HIDDEN) / 256, 256, 0, stream>>>(partial, pooled, nchunks);
  router_k<<<BATCH, 256, 0, stream>>>(pooled, W1, b1, lng, lnb, W2, b2, out);
}